// Round 1
// baseline (349.663 us; speedup 1.0000x reference)
//
#include <hip/hip_runtime.h>
#include <math.h>

// ChannelDropout: out[b,c,t] = sig[b,c,t] * kept[b,c] / (1e-8 + proba[b,c])
//   kept[b,c]  = ||pos[b,c] - center|| > 0.2
//   proba[b,c] = mean_i( ||pos[b,c] - mc[i]|| > 0.2 ), i in [0,100)
//
// One block per (b,c) row. Wave 0 computes the per-channel scale (parallel
// over MC centers + shuffle reduce), broadcast via LDS, then all 256 threads
// stream the T=3000 row with float4 loads/stores. Memory-bound: ~419 MB HBM
// traffic total.

__global__ __launch_bounds__(256) void channel_dropout_kernel(
    const float* __restrict__ sig,
    const float* __restrict__ pos,
    const float* __restrict__ center,
    const float* __restrict__ mc,
    float* __restrict__ out,
    int T, int NMC)
{
    const int row = blockIdx.x;           // b*C + c
    const int t   = threadIdx.x;
    __shared__ float s_scale;

    if (t < 64) {
        const float px = pos[2 * row + 0];
        const float py = pos[2 * row + 1];
        // parallel Monte-Carlo indicator count across 64 lanes
        float cnt = 0.0f;
        for (int i = t; i < NMC; i += 64) {
            const float dx = px - mc[2 * i + 0];
            const float dy = py - mc[2 * i + 1];
            cnt += (sqrtf(dx * dx + dy * dy) > 0.2f) ? 1.0f : 0.0f;
        }
        // wave-64 butterfly reduce
        #pragma unroll
        for (int off = 32; off > 0; off >>= 1)
            cnt += __shfl_down(cnt, off, 64);
        if (t == 0) {
            const float dx = px - center[0];
            const float dy = py - center[1];
            const float kept =
                (sqrtf(dx * dx + dy * dy) > 0.2f) ? 1.0f : 0.0f;
            const float proba = cnt / (float)NMC;
            s_scale = kept / (1e-8f + proba);
        }
    }
    __syncthreads();
    const float scale = s_scale;

    const size_t base = (size_t)row * (size_t)T;
    const int n4 = T >> 2;                 // 750 float4 per row
    const float4* __restrict__ in4  = (const float4*)(sig + base);
    float4* __restrict__       out4 = (float4*)(out + base);

    for (int i = t; i < n4; i += 256) {
        float4 v = in4[i];
        v.x *= scale; v.y *= scale; v.z *= scale; v.w *= scale;
        out4[i] = v;
    }
    // tail for T % 4 != 0 (not hit for T=3000, kept for safety)
    for (int i = (n4 << 2) + t; i < T; i += 256) {
        out[base + i] = sig[base + i] * scale;
    }
}

extern "C" void kernel_launch(void* const* d_in, const int* in_sizes, int n_in,
                              void* d_out, int out_size, void* d_ws, size_t ws_size,
                              hipStream_t stream) {
    const float* sig    = (const float*)d_in[0];  // (B, C, T) f32
    const float* pos    = (const float*)d_in[1];  // (B, C, 2) f32
    const float* center = (const float*)d_in[2];  // (2,)      f32
    const float* mc     = (const float*)d_in[3];  // (N, 2)    f32
    float* out          = (float*)d_out;          // (B, C, T) f32

    const int rows = in_sizes[1] / 2;             // B*C = 17472
    const int T    = in_sizes[0] / rows;          // 3000
    const int NMC  = in_sizes[3] / 2;             // 100

    channel_dropout_kernel<<<rows, 256, 0, stream>>>(
        sig, pos, center, mc, out, T, NMC);
}